// Round 17
// baseline (156.758 us; speedup 1.0000x reference)
//
#include <hip/hip_runtime.h>
#include <stdint.h>

typedef __attribute__((ext_vector_type(8))) short short8;
typedef __attribute__((ext_vector_type(4))) float f32x4;
typedef _Float16 h2t __attribute__((ext_vector_type(2)));
typedef _Float16 h4t __attribute__((ext_vector_type(4)));

#define MFMA_BF16(a, b, c) __builtin_amdgcn_mfma_f32_16x16x32_bf16((a), (b), (c), 0, 0, 0)
#define MFMA16(a, b, c)    __builtin_amdgcn_mfma_f32_16x16x16f16((a), (b), (c), 0, 0, 0)

// ============================ common helpers ============================

__device__ __forceinline__ h2t pkh2(float a, float b) {
  auto t = __builtin_amdgcn_cvt_pkrtz(a, b);
  return __builtin_bit_cast(h2t, t);
}
__device__ __forceinline__ uint32_t pkh2u(float a, float b) {
  auto t = __builtin_amdgcn_cvt_pkrtz(a, b);
  return __builtin_bit_cast(uint32_t, t);
}

__device__ __forceinline__ uint32_t pkbf16(float lo, float hi) {
  uint32_t r;
  asm("v_cvt_pk_bf16_f32 %0, %1, %2" : "=v"(r) : "v"(lo), "v"(hi));
  return r;
}
__device__ __forceinline__ uint16_t bf1(float f) { return (uint16_t)pkbf16(f, f); }

__device__ __forceinline__ uint16_t bf16u(float f) {
  union { float f; uint32_t u; } cv; cv.f = f;
  uint32_t r = cv.u + 0x7fffu + ((cv.u >> 16) & 1u);
  return (uint16_t)(r >> 16);
}

__device__ __forceinline__ short8 pack8(const float* v) {
  union { short8 s; uint32_t u[4]; } r;
#pragma unroll
  for (int j = 0; j < 4; ++j) r.u[j] = pkbf16(v[2 * j], v[2 * j + 1]);
  return r.s;
}

// packed f16 rcp / exp2 via per-half trans ops
__device__ __forceinline__ h2t rcp2(h2t v) {
  uint32_t x = __builtin_bit_cast(uint32_t, v);
  uint32_t xh = x >> 16;
  uint32_t rlo, rhi, r;
  asm("v_rcp_f16 %0, %1" : "=v"(rlo) : "v"(x));
  asm("v_rcp_f16 %0, %1" : "=v"(rhi) : "v"(xh));
  asm("v_pack_b32_f16 %0, %1, %2" : "=v"(r) : "v"(rlo), "v"(rhi));
  return __builtin_bit_cast(h2t, r);
}
__device__ __forceinline__ h2t exp22(h2t v) {
  uint32_t x = __builtin_bit_cast(uint32_t, v);
  uint32_t xh = x >> 16;
  uint32_t rlo, rhi, r;
  asm("v_exp_f16 %0, %1" : "=v"(rlo) : "v"(x));
  asm("v_exp_f16 %0, %1" : "=v"(rhi) : "v"(xh));
  asm("v_pack_b32_f16 %0, %1, %2" : "=v"(r) : "v"(rlo), "v"(rhi));
  return __builtin_bit_cast(h2t, r);
}

// packed GELU, sigmoid form: gelu(x) = x * rcp(1 + exp2(x*(-2.302588 - 0.1029634 x^2)))
__device__ __forceinline__ h2t gelu_h2(h2t x) {
  h2t x2 = x * x;
  h2t q  = x2 * (_Float16)(-0.1029634f) + (_Float16)(-2.3025881f);
  h2t w  = x * q;
  h2t e  = exp22(w);
  h2t d  = e + (_Float16)1.0f;
  h2t r  = rcp2(d);
  return x * r;
}

__device__ __forceinline__ float gelu_f(float x) {
  float x2 = x * x;
  float q  = __builtin_fmaf(x2, -0.1029634f, -2.3025881f);
  float w  = x * q;
  float d  = 1.0f + __builtin_amdgcn_exp2f(w);
  return x * __builtin_amdgcn_rcpf(d);
}

__device__ __forceinline__ float sigmoid_f(float x) {
  return __builtin_amdgcn_rcpf(1.0f + __builtin_amdgcn_exp2f(-1.44269504f * x));
}

__device__ __forceinline__ h4t gelupack(f32x4 a) {
  h2t v01 = gelu_h2(pkh2(a[0], a[1]));
  h2t v23 = gelu_h2(pkh2(a[2], a[3]));
  return __builtin_shufflevector(v01, v23, 0, 1, 2, 3);
}

// bf16 staging (fallback kernel)
__device__ void stage_mat(const float* __restrict__ W, int Kact, int KT, int NT, int N,
                          uint16_t* __restrict__ dst) {
  int cnt = KT * NT * 512;
  for (int i = threadIdx.x; i < cnt; i += blockDim.x) {
    int e = i & 7;
    int lane = (i >> 3) & 63;
    int q = i >> 9;
    int nt = q % NT;
    int kt = q / NT;
    int k = kt * 32 + ((lane >> 4) << 3) + e;
    int n = nt * 16 + (lane & 15);
    float v = (k < Kact) ? W[k * N + n] : 0.0f;
    dst[i] = bf16u(v);
  }
}

__device__ __forceinline__ short8 ldfrag(const uint16_t* wf, int off, int lane) {
  return *(const short8*)(wf + off + lane * 8);
}
__device__ __forceinline__ h4t ldA(const uint16_t* sm, int base, int tile, int lane) {
  return *(const h4t*)(sm + base + tile * 256 + lane * 4);
}

// ============================ blob layout ============================
#define W_GW2 0
#define W_OW2 2048
#define W_HW1 4096
#define W_HW2 12288
#define W_CW1 14336
#define W_ELEMS 14848
#define B_GB2 0
#define B_OB2 4
#define B_HB1 8
#define B_HB2 12
#define B_CB1 14
#define BIAS_OFF (W_ELEMS * 2)
#define ENC_OFF (BIAS_OFF + 960)
#define BLOB_BYTES (ENC_OFF + 768)
#define PREP_ITEMS (W_ELEMS + 240 + 192)

// ws ints: [0..2] counts, [4..6] scatter cursors, [8..10] seg base,
// [11..13] seg tile count, [32..] idx buf

// ============================ fused count (int4, LDS-aggregated) + blob-prep ============================
__global__ void prep_k(const int* __restrict__ levels, int N, int pblocks,
                       const float* __restrict__ g_w1, const float* __restrict__ g_b1,
                       const float* __restrict__ o_w1, const float* __restrict__ o_b1,
                       const float* __restrict__ g_w2, const float* __restrict__ o_w2,
                       const float* __restrict__ h_w1, const float* __restrict__ h_w2,
                       const float* __restrict__ c_w1,
                       const float* __restrict__ g_b2, const float* __restrict__ o_b2,
                       const float* __restrict__ h_b1, const float* __restrict__ h_b2,
                       const float* __restrict__ c_b1,
                       int* __restrict__ ws, char* __restrict__ wb) {
  if ((int)blockIdx.x < pblocks) {
    __shared__ int bc[3];
    if (threadIdx.x < 3) bc[threadIdx.x] = 0;
    __syncthreads();
    int base = ((int)blockIdx.x * 512 + (int)threadIdx.x) * 4;
    int e0 = -1, e1 = -1, e2 = -1, e3 = -1;
    if (base + 3 < N) {
      int4 v = *(const int4*)(levels + base);
      e0 = v.x; e1 = v.y; e2 = v.z; e3 = v.w;
    } else {
      if (base < N)     e0 = levels[base];
      if (base + 1 < N) e1 = levels[base + 1];
      if (base + 2 < N) e2 = levels[base + 2];
      if (base + 3 < N) e3 = levels[base + 3];
    }
    int lane = threadIdx.x & 63;
#pragma unroll
    for (int l = 0; l < 3; ++l) {
      int cnt = (e0 == l) + (e1 == l) + (e2 == l) + (e3 == l);
#pragma unroll
      for (int d = 1; d < 64; d <<= 1) cnt += __shfl_xor(cnt, d);
      if (lane == 0 && cnt) atomicAdd(&bc[l], cnt);
    }
    __syncthreads();
    if (threadIdx.x < 3 && bc[threadIdx.x]) atomicAdd(&ws[threadIdx.x], bc[threadIdx.x]);
    return;
  }
  int i = ((int)blockIdx.x - pblocks) * 512 + threadIdx.x;
  if (i >= 3 * PREP_ITEMS) return;
  int lv = i / PREP_ITEMS;
  int off = i - lv * PREP_ITEMS;
  char* blob = wb + (size_t)lv * BLOB_BYTES;
  if (off < W_ELEMS) {
    int e = off & 3;
    int lane = (off >> 2) & 63;
    int tile = off >> 8;
    const float* W; int NT, N2, tb;
    if (tile < 8)       { W = g_w2;             NT = 4; N2 = 64; tb = tile; }
    else if (tile < 16) { W = o_w2;             NT = 4; N2 = 64; tb = tile - 8; }
    else if (tile < 48) { W = h_w1 + lv * 8192; NT = 4; N2 = 64; tb = tile - 16; }
    else if (tile < 56) { W = h_w2 + lv * 2048; NT = 2; N2 = 32; tb = tile - 48; }
    else                { W = c_w1;             NT = 1; N2 = 16; tb = tile - 56; }
    int nt = tb % NT, kt = tb / NT;
    int k = kt * 16 + ((lane >> 4) << 2) + e;
    int n = nt * 16 + (lane & 15);
    _Float16 h = (_Float16)W[k * N2 + n];
    ((uint16_t*)blob)[off] = __builtin_bit_cast(unsigned short, h);
  } else if (off < W_ELEMS + 240) {
    int b = off - W_ELEMS;
    int fi = b & 15;
    int t = b >> 4;
    const float* B; int base;
    if (t < 4)       { B = g_b2;            base = t * 16; }
    else if (t < 8)  { B = o_b2;            base = (t - 4) * 16; }
    else if (t < 12) { B = h_b1 + lv * 64;  base = (t - 8) * 16; }
    else if (t < 14) { B = h_b2 + lv * 32;  base = (t - 12) * 16; }
    else             { B = c_b1;            base = 0; }
    ((float*)(blob + BIAS_OFF))[b] = B[base + fi];
  } else {
    int e2 = off - (W_ELEMS + 240);   // 0..191
    int gg = e2 / 48, slot = e2 % 48;
    int k = 0, p;
    const float* src; bool isb = false;
    if (slot < 20)      { src = g_w1; k = slot >> 2; p = slot & 3; }
    else if (slot < 40) { src = o_w1; k = (slot - 20) >> 2; p = (slot - 20) & 3; }
    else if (slot < 44) { src = g_b1; p = slot - 40; isb = true; }
    else                { src = o_b1; p = slot - 44; isb = true; }
    int f0 = (p >> 1) * 16 + gg * 4 + (p & 1) * 2;
    float a, b;
    if (isb) { a = src[f0]; b = src[f0 + 1]; }
    else     { a = src[k * 32 + f0]; b = src[k * 32 + f0 + 1]; }
    ((uint32_t*)(blob + ENC_OFF))[e2] = pkh2u(a, b);
  }
}

// ============================ scatter (int4 x4/thread, wave scan) ============================
__global__ void scatter_k(const int* __restrict__ levels, int* __restrict__ ws, int N) {
  int cntl[3], padl[3], Bl[3];
  cntl[0] = ws[0]; cntl[1] = ws[1]; cntl[2] = ws[2];
#pragma unroll
  for (int l = 0; l < 3; ++l) padl[l] = (cntl[l] + 31) & ~31;
  Bl[0] = 0; Bl[1] = padl[0]; Bl[2] = padl[0] + padl[1];
  int* idx = ws + 32;
  if (blockIdx.x == 0) {
    if (threadIdx.x < 3) {
      ws[8 + threadIdx.x] = Bl[threadIdx.x];
      ws[11 + threadIdx.x] = padl[threadIdx.x] >> 5;
    }
#pragma unroll
    for (int l = 0; l < 3; ++l)
      for (int s = cntl[l] + (int)threadIdx.x; s < padl[l]; s += 512) idx[Bl[l] + s] = -1;
  }

  const int lane = threadIdx.x & 63;
  const int wave = threadIdx.x >> 6;
  int base = ((int)blockIdx.x * 512 + (int)threadIdx.x) * 4;
  int e0 = -1, e1 = -1, e2 = -1, e3 = -1;
  if (base + 3 < N) {
    int4 v = *(const int4*)(levels + base);
    e0 = v.x; e1 = v.y; e2 = v.z; e3 = v.w;
  } else {
    if (base < N)     e0 = levels[base];
    if (base + 1 < N) e1 = levels[base + 1];
    if (base + 2 < N) e2 = levels[base + 2];
    if (base + 3 < N) e3 = levels[base + 3];
  }

  __shared__ int wsum[3][8];
  __shared__ int bb[3];
  int texcl0, texcl1, texcl2;
#pragma unroll
  for (int l = 0; l < 3; ++l) {
    int cnt = (e0 == l) + (e1 == l) + (e2 == l) + (e3 == l);
    int v = cnt;
#pragma unroll
    for (int d = 1; d < 64; d <<= 1) {
      int t = __shfl_up(v, d);
      v += (lane >= d) ? t : 0;
    }
    int ex = v - cnt;
    if (l == 0) texcl0 = ex; else if (l == 1) texcl1 = ex; else texcl2 = ex;
    if (lane == 63) wsum[l][wave] = v;
  }
  __syncthreads();
  if (threadIdx.x < 3) {
    int l = threadIdx.x, s = 0;
#pragma unroll
    for (int w = 0; w < 8; ++w) { int t = wsum[l][w]; wsum[l][w] = s; s += t; }
    bb[l] = atomicAdd(&ws[4 + l], s);
  }
  __syncthreads();

  int p0 = Bl[0] + bb[0] + wsum[0][wave] + texcl0;
  int p1 = Bl[1] + bb[1] + wsum[1][wave] + texcl1;
  int p2 = Bl[2] + bb[2] + wsum[2][wave] + texcl2;
#define EMIT(E, K) do {                                  \
    if ((E) == 0)      idx[p0++] = base + (K);           \
    else if ((E) == 1) idx[p1++] = base + (K);           \
    else if ((E) == 2) idx[p2++] = base + (K);           \
  } while (0)
  EMIT(e0, 0);
  EMIT(e1, 1);
  EMIT(e2, 2);
  EMIT(e3, 3);
#undef EMIT
}

// ============================ routed main kernel ============================
#define NBL 1376                 // blocks per level; grid = 4128; 11008 wave-slots/level
#define JS (8 * NBL)             // j-stride per wave
#define R_SMEM BLOB_BYTES        // 31424 B

__device__ __forceinline__ f32x4 ldbias(const float* bp, int tile, int g) {
  return *(const f32x4*)(bp + tile * 16 + g * 4);
}

// load one row's 10 feats (rid<0 -> row 0, output suppressed later)
#define LOADT(FBUF, RID) do {                                                   \
    const float2* _p = (const float2*)(feats + (size_t)((RID) < 0 ? 0 : (RID)) * 10); \
    _Pragma("unroll")                                                           \
    for (int _i = 0; _i < 5; ++_i) FBUF[_i] = _p[_i];                           \
  } while (0)

// full per-tile network; FBUF = float2[5] (static idx), RIDX = row index or -1
#define TILE_BODY(FBUF, RIDX) do {                                              \
    _Float16 fv[10];                                                            \
    _Pragma("unroll")                                                           \
    for (int i2 = 0; i2 < 5; ++i2) {                                            \
      fv[2 * i2]     = (_Float16)FBUF[i2].x;                                    \
      fv[2 * i2 + 1] = (_Float16)FBUF[i2].y;                                    \
    }                                                                           \
    h2t agp[4], aop[4];                                                         \
    _Pragma("unroll")                                                           \
    for (int p = 0; p < 4; ++p) {                                               \
      h2t a = b1g[p];                                                           \
      _Pragma("unroll")                                                         \
      for (int k = 0; k < 5; ++k) a = w1g[k][p] * fv[k] + a;                    \
      agp[p] = gelu_h2(a);                                                      \
      h2t ao = b1o[p];                                                          \
      _Pragma("unroll")                                                         \
      for (int k = 0; k < 5; ++k) ao = w1o[k][p] * fv[5 + k] + ao;              \
      aop[p] = gelu_h2(ao);                                                     \
    }                                                                           \
    h4t agf[2], aof[2];                                                         \
    _Pragma("unroll")                                                           \
    for (int t = 0; t < 2; ++t) {                                               \
      agf[t] = __builtin_shufflevector(agp[2 * t], agp[2 * t + 1], 0, 1, 2, 3); \
      aof[t] = __builtin_shufflevector(aop[2 * t], aop[2 * t + 1], 0, 1, 2, 3); \
    }                                                                           \
    h4t xf[8];                                                                  \
    _Pragma("unroll")                                                           \
    for (int nt = 0; nt < 4; ++nt) {                                            \
      f32x4 acc = ldbias(bp, B_GB2 + nt, g);                                    \
      acc = MFMA16(ldA(sm, W_GW2, 0 * 4 + nt, lane), agf[0], acc);              \
      acc = MFMA16(ldA(sm, W_GW2, 1 * 4 + nt, lane), agf[1], acc);              \
      xf[nt] = gelupack(acc);                                                   \
    }                                                                           \
    _Pragma("unroll")                                                           \
    for (int nt = 0; nt < 4; ++nt) {                                            \
      f32x4 acc = ldbias(bp, B_OB2 + nt, g);                                    \
      acc = MFMA16(ldA(sm, W_OW2, 0 * 4 + nt, lane), aof[0], acc);              \
      acc = MFMA16(ldA(sm, W_OW2, 1 * 4 + nt, lane), aof[1], acc);              \
      xf[4 + nt] = gelupack(acc);                                               \
    }                                                                           \
    h4t hf[4];                                                                  \
    _Pragma("unroll")                                                           \
    for (int nt = 0; nt < 4; ++nt) {                                            \
      f32x4 acc = ldbias(bp, B_HB1 + nt, g);                                    \
      _Pragma("unroll")                                                         \
      for (int kt = 0; kt < 8; ++kt)                                            \
        acc = MFMA16(ldA(sm, W_HW1, kt * 4 + nt, lane), xf[kt], acc);           \
      hf[nt] = gelupack(acc);                                                   \
    }                                                                           \
    h4t cf[2];                                                                  \
    _Pragma("unroll")                                                           \
    for (int nt = 0; nt < 2; ++nt) {                                            \
      f32x4 acc = ldbias(bp, B_HB2 + nt, g);                                    \
      _Pragma("unroll")                                                         \
      for (int kt = 0; kt < 4; ++kt)                                            \
        acc = MFMA16(ldA(sm, W_HW2, kt * 2 + nt, lane), hf[kt], acc);           \
      cf[nt] = gelupack(acc);                                                   \
    }                                                                           \
    {                                                                           \
      f32x4 acc = ldbias(bp, B_CB1, g);                                         \
      acc = MFMA16(ldA(sm, W_CW1, 0, lane), cf[0], acc);                        \
      acc = MFMA16(ldA(sm, W_CW1, 1, lane), cf[1], acc);                        \
      float s = 0.0f;                                                           \
      _Pragma("unroll")                                                         \
      for (int r = 0; r < 4; ++r) s = __builtin_fmaf(gelu_f(acc[r]), w2v[r], s);\
      s += __shfl_xor(s, 16);                                                   \
      s += __shfl_xor(s, 32);                                                   \
      if (g == 0 && (RIDX) >= 0) out[(RIDX)] = sigmoid_f(s + cb2v);             \
    }                                                                           \
  } while (0)

__global__ __launch_bounds__(512, 2) void spe_routed(
    const float* __restrict__ feats, const int* __restrict__ ws,
    const char* __restrict__ wb,
    const float* __restrict__ c_w2, const float* __restrict__ c_b2,
    float* __restrict__ out) {
  extern __shared__ uint16_t sm[];
  const int lv = blockIdx.x % 3;
  const int bi = blockIdx.x / 3;

  // stage pre-built blob (straight vectorized copy)
  {
    const uint4* src = (const uint4*)(wb + (size_t)lv * BLOB_BYTES);
    uint4* dst = (uint4*)sm;
    for (int i = threadIdx.x; i < BLOB_BYTES / 16; i += 512) dst[i] = src[i];
  }
  __syncthreads();
  const float* bp = (const float*)((const char*)sm + BIAS_OFF);

  const int lane = threadIdx.x & 63;
  const int wave = threadIdx.x >> 6;
  const int c = lane & 15;
  const int g = lane >> 4;
  const int* idxb = ws + 32;
  const int segrow = ws[8 + lv];
  const int ntl = ws[11 + lv];

  // ---- encL1 weights/biases from LDS packed table (broadcast reads) ----
  uint32_t et[48];
  {
    const uint32_t* ep = (const uint32_t*)((const char*)sm + ENC_OFF) + g * 48;
#pragma unroll
    for (int i = 0; i < 48; ++i) et[i] = ep[i];
  }
  h2t w1g[5][4], w1o[5][4], b1g[4], b1o[4];
#pragma unroll
  for (int k = 0; k < 5; ++k)
#pragma unroll
    for (int p = 0; p < 4; ++p) {
      w1g[k][p] = __builtin_bit_cast(h2t, et[k * 4 + p]);
      w1o[k][p] = __builtin_bit_cast(h2t, et[20 + k * 4 + p]);
    }
#pragma unroll
  for (int p = 0; p < 4; ++p) {
    b1g[p] = __builtin_bit_cast(h2t, et[40 + p]);
    b1o[p] = __builtin_bit_cast(h2t, et[44 + p]);
  }
  float w2v[4];
#pragma unroll
  for (int r = 0; r < 4; ++r) w2v[r] = c_w2[g * 4 + r];
  const float cb2v = c_b2[0];

  // ---- main loop: one 32-row j-slot per wave; both gathers issued up front ----
  for (int j = bi * 8 + wave; j < ntl; j += JS) {
    const int rb = segrow + (j << 5);
    const int r0 = idxb[rb + c];
    const int r1 = idxb[rb + 16 + c];
    float2 f0[5], f1[5];
    LOADT(f0, r0);
    LOADT(f1, r1);        // resolves under TILE_BODY(f0)'s ~2500-cycle compute
    TILE_BODY(f0, r0);
    TILE_BODY(f1, r1);
  }
}

// ============================ flat fallback (bf16) ============================
#define GW2F 0
#define OW2F 2048
#define HW1F 4096
#define HW2F 28672
#define CW1F 34816
#define WFRAG_ELEMS 35328
#define STAGE_PER_WAVE 4352
#define SMEM_BYTES ((WFRAG_ELEMS + 8 * STAGE_PER_WAVE) * 2)

__global__ __launch_bounds__(512, 2) void spe_flat(
    const float* __restrict__ feats, const int* __restrict__ levels,
    const float* __restrict__ g_w1, const float* __restrict__ g_b1,
    const float* __restrict__ g_w2, const float* __restrict__ g_b2,
    const float* __restrict__ o_w1, const float* __restrict__ o_b1,
    const float* __restrict__ o_w2, const float* __restrict__ o_b2,
    const float* __restrict__ h_w1, const float* __restrict__ h_b1,
    const float* __restrict__ h_w2, const float* __restrict__ h_b2,
    const float* __restrict__ c_w1, const float* __restrict__ c_b1,
    const float* __restrict__ c_w2, const float* __restrict__ c_b2,
    float* __restrict__ out) {
  extern __shared__ uint16_t sm[];
  uint16_t* wf = sm;
  stage_mat(g_w2, 32, 1, 4, 64, wf + GW2F);
  stage_mat(o_w2, 32, 1, 4, 64, wf + OW2F);
#pragma unroll
  for (int h = 0; h < 3; ++h) {
    stage_mat(h_w1 + h * 8192, 128, 4, 4, 64, wf + HW1F + h * 8192);
    stage_mat(h_w2 + h * 2048, 64, 2, 2, 32, wf + HW2F + h * 2048);
  }
  stage_mat(c_w1, 32, 1, 1, 16, wf + CW1F);
  __syncthreads();

  const int lane = threadIdx.x & 63;
  const int wave = threadIdx.x >> 6;
  const int c = lane & 15;
  const int g = lane >> 4;
  const int j0 = g << 3;
  uint16_t* xb = sm + WFRAG_ELEMS + wave * STAGE_PER_WAVE;

  float gb1v[8], ob1v[8];
#pragma unroll
  for (int jj = 0; jj < 8; ++jj) { gb1v[jj] = g_b1[j0 + jj]; ob1v[jj] = o_b1[j0 + jj]; }
  float gb2v[4], ob2v[4];
#pragma unroll
  for (int nt = 0; nt < 4; ++nt) { gb2v[nt] = g_b2[nt * 16 + c]; ob2v[nt] = o_b2[nt * 16 + c]; }
  float hb1v[3][4], hb2v[3][2];
#pragma unroll
  for (int h = 0; h < 3; ++h) {
#pragma unroll
    for (int nt = 0; nt < 4; ++nt) hb1v[h][nt] = h_b1[h * 64 + nt * 16 + c];
#pragma unroll
    for (int n2 = 0; n2 < 2; ++n2) hb2v[h][n2] = h_b2[h * 32 + n2 * 16 + c];
  }
  const float cb1v = c_b1[c];
  const float w2v  = c_w2[c];
  const float cb2v = c_b2[0];

  for (int it = 0; it < 4; ++it) {
    const int rowbase = ((blockIdx.x * 8 + wave) * 4 + it) * 32;
    short8 afx[2][4];
    int lvl[2][4];
#pragma unroll
    for (int tt = 0; tt < 2; ++tt) {
      const int tb = rowbase + tt * 16;
      const float* fr = feats + (size_t)(tb + c) * 10;
      float f[10];
#pragma unroll
      for (int i = 0; i < 10; ++i) f[i] = fr[i];
      float h1[8];
#pragma unroll
      for (int jj = 0; jj < 8; ++jj) {
        float a = gb1v[jj];
#pragma unroll
        for (int k = 0; k < 5; ++k) a = __builtin_fmaf(f[k], g_w1[k * 32 + j0 + jj], a);
        h1[jj] = gelu_f(a);
      }
      short8 ag = pack8(h1);
#pragma unroll
      for (int jj = 0; jj < 8; ++jj) {
        float a = ob1v[jj];
#pragma unroll
        for (int k = 0; k < 5; ++k) a = __builtin_fmaf(f[5 + k], o_w1[k * 32 + j0 + jj], a);
        h1[jj] = gelu_f(a);
      }
      short8 ao = pack8(h1);
#pragma unroll
      for (int nt = 0; nt < 4; ++nt) {
        f32x4 acc = {0.f, 0.f, 0.f, 0.f};
        acc = MFMA_BF16(ag, ldfrag(wf, GW2F + nt * 512, lane), acc);
#pragma unroll
        for (int r = 0; r < 4; ++r)
          xb[(tt * 16 + g * 4 + r) * 136 + nt * 16 + c] = bf1(gelu_f(acc[r] + gb2v[nt]));
      }
#pragma unroll
      for (int nt = 0; nt < 4; ++nt) {
        f32x4 acc = {0.f, 0.f, 0.f, 0.f};
        acc = MFMA_BF16(ao, ldfrag(wf, OW2F + nt * 512, lane), acc);
#pragma unroll
        for (int r = 0; r < 4; ++r)
          xb[(tt * 16 + g * 4 + r) * 136 + 64 + nt * 16 + c] = bf1(gelu_f(acc[r] + ob2v[nt]));
      }
#pragma unroll
      for (int kt = 0; kt < 4; ++kt)
        afx[tt][kt] = *(const short8*)(xb + (tt * 16 + c) * 136 + kt * 32 + g * 8);
#pragma unroll
      for (int r = 0; r < 4; ++r) lvl[tt][r] = levels[tb + g * 4 + r];
    }
    float sel[2][2][4];
#pragma unroll
    for (int h = 0; h < 3; ++h) {
      f32x4 a1[2][4];
#pragma unroll
      for (int nt = 0; nt < 4; ++nt) {
        a1[0][nt] = (f32x4){0.f, 0.f, 0.f, 0.f};
        a1[1][nt] = (f32x4){0.f, 0.f, 0.f, 0.f};
#pragma unroll
        for (int kt = 0; kt < 4; ++kt) {
          short8 bfr = ldfrag(wf, HW1F + h * 8192 + (kt * 4 + nt) * 512, lane);
          a1[0][nt] = MFMA_BF16(afx[0][kt], bfr, a1[0][nt]);
          a1[1][nt] = MFMA_BF16(afx[1][kt], bfr, a1[1][nt]);
        }
      }
#pragma unroll
      for (int tt = 0; tt < 2; ++tt)
#pragma unroll
        for (int nt = 0; nt < 4; ++nt)
#pragma unroll
          for (int r = 0; r < 4; ++r)
            xb[(tt * 16 + g * 4 + r) * 136 + nt * 16 + c] = bf1(gelu_f(a1[tt][nt][r] + hb1v[h][nt]));
      short8 afh[2][2];
#pragma unroll
      for (int tt = 0; tt < 2; ++tt)
#pragma unroll
        for (int kt = 0; kt < 2; ++kt)
          afh[tt][kt] = *(const short8*)(xb + (tt * 16 + c) * 136 + kt * 32 + g * 8);
      f32x4 a2[2][2];
#pragma unroll
      for (int n2 = 0; n2 < 2; ++n2) {
        a2[0][n2] = (f32x4){0.f, 0.f, 0.f, 0.f};
        a2[1][n2] = (f32x4){0.f, 0.f, 0.f, 0.f};
#pragma unroll
        for (int kt = 0; kt < 2; ++kt) {
          short8 bfr = ldfrag(wf, HW2F + h * 2048 + (kt * 2 + n2) * 512, lane);
          a2[0][n2] = MFMA_BF16(afh[0][kt], bfr, a2[0][n2]);
          a2[1][n2] = MFMA_BF16(afh[1][kt], bfr, a2[1][n2]);
        }
      }
#pragma unroll
      for (int tt = 0; tt < 2; ++tt)
#pragma unroll
        for (int n2 = 0; n2 < 2; ++n2)
#pragma unroll
          for (int r = 0; r < 4; ++r) {
            float v = gelu_f(a2[tt][n2][r] + hb2v[h][n2]);
            if (h == 0) sel[tt][n2][r] = v;
            else        sel[tt][n2][r] = (lvl[tt][r] == h) ? v : sel[tt][n2][r];
          }
    }
#pragma unroll
    for (int tt = 0; tt < 2; ++tt)
#pragma unroll
      for (int n2 = 0; n2 < 2; ++n2)
#pragma unroll
        for (int r = 0; r < 4; ++r)
          xb[(tt * 16 + g * 4 + r) * 136 + n2 * 16 + c] = bf1(sel[tt][n2][r]);
    short8 cwf = ldfrag(wf, CW1F, lane);
#pragma unroll
    for (int tt = 0; tt < 2; ++tt) {
      short8 afc = *(const short8*)(xb + (tt * 16 + c) * 136 + g * 8);
      f32x4 acc = {0.f, 0.f, 0.f, 0.f};
      acc = MFMA_BF16(afc, cwf, acc);
      float p[4];
#pragma unroll
      for (int r = 0; r < 4; ++r) p[r] = gelu_f(acc[r] + cb1v) * w2v;
#pragma unroll
      for (int m = 1; m < 16; m <<= 1)
#pragma unroll
        for (int r = 0; r < 4; ++r) p[r] += __shfl_xor(p[r], m);
      if (c == 0) {
        float4 o4;
        o4.x = sigmoid_f(p[0] + cb2v);
        o4.y = sigmoid_f(p[1] + cb2v);
        o4.z = sigmoid_f(p[2] + cb2v);
        o4.w = sigmoid_f(p[3] + cb2v);
        *(float4*)(out + rowbase + tt * 16 + g * 4) = o4;
      }
    }
  }
}

// ============================ launch ============================

extern "C" void kernel_launch(void* const* d_in, const int* in_sizes, int n_in,
                              void* d_out, int out_size, void* d_ws, size_t ws_size,
                              hipStream_t stream) {
  (void)n_in; (void)out_size;
  const float* feats  = (const float*)d_in[0];
  const int*   levels = (const int*)d_in[1];
  const float* g_w1 = (const float*)d_in[2];
  const float* g_b1 = (const float*)d_in[3];
  const float* g_w2 = (const float*)d_in[4];
  const float* g_b2 = (const float*)d_in[5];
  const float* o_w1 = (const float*)d_in[6];
  const float* o_b1 = (const float*)d_in[7];
  const float* o_w2 = (const float*)d_in[8];
  const float* o_b2 = (const float*)d_in[9];
  const float* h_w1 = (const float*)d_in[10];
  const float* h_b1 = (const float*)d_in[11];
  const float* h_w2 = (const float*)d_in[12];
  const float* h_b2 = (const float*)d_in[13];
  const float* c_w1 = (const float*)d_in[14];
  const float* c_b1 = (const float*)d_in[15];
  const float* c_w2 = (const float*)d_in[16];
  const float* c_b2 = (const float*)d_in[17];
  float* out = (float*)d_out;
  const int N = in_sizes[1];

  size_t wboff = (((size_t)(32 + N + 96) * sizeof(int)) + 255) & ~(size_t)255;
  size_t need = wboff + (size_t)3 * BLOB_BYTES;
  if (d_ws != nullptr && ws_size >= need) {
    int* ws = (int*)d_ws;
    char* wb = (char*)d_ws + wboff;
    (void)hipMemsetAsync(ws, 0, 128, stream);
    int pblocks = (N + 2047) / 2048;   // 4 elems/thread
    int prepb = (3 * PREP_ITEMS + 511) / 512;
    prep_k<<<pblocks + prepb, 512, 0, stream>>>(
        levels, N, pblocks, g_w1, g_b1, o_w1, o_b1,
        g_w2, o_w2, h_w1, h_w2, c_w1, g_b2, o_b2, h_b1, h_b2, c_b1, ws, wb);
    scatter_k<<<pblocks, 512, 0, stream>>>(levels, ws, N);
    (void)hipFuncSetAttribute(reinterpret_cast<const void*>(spe_routed),
                              hipFuncAttributeMaxDynamicSharedMemorySize, R_SMEM);
    spe_routed<<<3 * NBL, 512, R_SMEM, stream>>>(feats, ws, wb, c_w2, c_b2, out);
  } else {
    (void)hipFuncSetAttribute(reinterpret_cast<const void*>(spe_flat),
                              hipFuncAttributeMaxDynamicSharedMemorySize, SMEM_BYTES);
    spe_flat<<<1024, 512, SMEM_BYTES, stream>>>(
        feats, levels, g_w1, g_b1, g_w2, g_b2, o_w1, o_b1, o_w2, o_b2,
        h_w1, h_b1, h_w2, h_b2, c_w1, c_b1, c_w2, c_b2, out);
  }
}

// Round 18
// 133.316 us; speedup vs baseline: 1.1758x; 1.1758x over previous
//
#include <hip/hip_runtime.h>
#include <stdint.h>

typedef __attribute__((ext_vector_type(8))) short short8;
typedef __attribute__((ext_vector_type(4))) float f32x4;
typedef _Float16 h2t __attribute__((ext_vector_type(2)));
typedef _Float16 h4t __attribute__((ext_vector_type(4)));

#define MFMA_BF16(a, b, c) __builtin_amdgcn_mfma_f32_16x16x32_bf16((a), (b), (c), 0, 0, 0)
#define MFMA16(a, b, c)    __builtin_amdgcn_mfma_f32_16x16x16f16((a), (b), (c), 0, 0, 0)

// ============================ common helpers ============================

__device__ __forceinline__ h2t pkh2(float a, float b) {
  auto t = __builtin_amdgcn_cvt_pkrtz(a, b);
  return __builtin_bit_cast(h2t, t);
}
__device__ __forceinline__ uint32_t pkh2u(float a, float b) {
  auto t = __builtin_amdgcn_cvt_pkrtz(a, b);
  return __builtin_bit_cast(uint32_t, t);
}

__device__ __forceinline__ uint32_t pkbf16(float lo, float hi) {
  uint32_t r;
  asm("v_cvt_pk_bf16_f32 %0, %1, %2" : "=v"(r) : "v"(lo), "v"(hi));
  return r;
}
__device__ __forceinline__ uint16_t bf1(float f) { return (uint16_t)pkbf16(f, f); }

__device__ __forceinline__ uint16_t bf16u(float f) {
  union { float f; uint32_t u; } cv; cv.f = f;
  uint32_t r = cv.u + 0x7fffu + ((cv.u >> 16) & 1u);
  return (uint16_t)(r >> 16);
}

__device__ __forceinline__ short8 pack8(const float* v) {
  union { short8 s; uint32_t u[4]; } r;
#pragma unroll
  for (int j = 0; j < 4; ++j) r.u[j] = pkbf16(v[2 * j], v[2 * j + 1]);
  return r.s;
}

// packed f16 rcp / exp2 via per-half trans ops
__device__ __forceinline__ h2t rcp2(h2t v) {
  uint32_t x = __builtin_bit_cast(uint32_t, v);
  uint32_t xh = x >> 16;
  uint32_t rlo, rhi, r;
  asm("v_rcp_f16 %0, %1" : "=v"(rlo) : "v"(x));
  asm("v_rcp_f16 %0, %1" : "=v"(rhi) : "v"(xh));
  asm("v_pack_b32_f16 %0, %1, %2" : "=v"(r) : "v"(rlo), "v"(rhi));
  return __builtin_bit_cast(h2t, r);
}
__device__ __forceinline__ h2t exp22(h2t v) {
  uint32_t x = __builtin_bit_cast(uint32_t, v);
  uint32_t xh = x >> 16;
  uint32_t rlo, rhi, r;
  asm("v_exp_f16 %0, %1" : "=v"(rlo) : "v"(x));
  asm("v_exp_f16 %0, %1" : "=v"(rhi) : "v"(xh));
  asm("v_pack_b32_f16 %0, %1, %2" : "=v"(r) : "v"(rlo), "v"(rhi));
  return __builtin_bit_cast(h2t, r);
}

// packed GELU, sigmoid form: gelu(x) = x * rcp(1 + exp2(x*(-2.302588 - 0.1029634 x^2)))
__device__ __forceinline__ h2t gelu_h2(h2t x) {
  h2t x2 = x * x;
  h2t q  = x2 * (_Float16)(-0.1029634f) + (_Float16)(-2.3025881f);
  h2t w  = x * q;
  h2t e  = exp22(w);
  h2t d  = e + (_Float16)1.0f;
  h2t r  = rcp2(d);
  return x * r;
}

__device__ __forceinline__ float gelu_f(float x) {
  float x2 = x * x;
  float q  = __builtin_fmaf(x2, -0.1029634f, -2.3025881f);
  float w  = x * q;
  float d  = 1.0f + __builtin_amdgcn_exp2f(w);
  return x * __builtin_amdgcn_rcpf(d);
}

__device__ __forceinline__ float sigmoid_f(float x) {
  return __builtin_amdgcn_rcpf(1.0f + __builtin_amdgcn_exp2f(-1.44269504f * x));
}

__device__ __forceinline__ h4t gelupack(f32x4 a) {
  h2t v01 = gelu_h2(pkh2(a[0], a[1]));
  h2t v23 = gelu_h2(pkh2(a[2], a[3]));
  return __builtin_shufflevector(v01, v23, 0, 1, 2, 3);
}

// bf16 staging (fallback kernel)
__device__ void stage_mat(const float* __restrict__ W, int Kact, int KT, int NT, int N,
                          uint16_t* __restrict__ dst) {
  int cnt = KT * NT * 512;
  for (int i = threadIdx.x; i < cnt; i += blockDim.x) {
    int e = i & 7;
    int lane = (i >> 3) & 63;
    int q = i >> 9;
    int nt = q % NT;
    int kt = q / NT;
    int k = kt * 32 + ((lane >> 4) << 3) + e;
    int n = nt * 16 + (lane & 15);
    float v = (k < Kact) ? W[k * N + n] : 0.0f;
    dst[i] = bf16u(v);
  }
}

__device__ __forceinline__ short8 ldfrag(const uint16_t* wf, int off, int lane) {
  return *(const short8*)(wf + off + lane * 8);
}
__device__ __forceinline__ h4t ldA(const uint16_t* sm, int base, int tile, int lane) {
  return *(const h4t*)(sm + base + tile * 256 + lane * 4);
}

// ============================ blob layout ============================
#define W_GW2 0
#define W_OW2 2048
#define W_HW1 4096
#define W_HW2 12288
#define W_CW1 14336
#define W_ELEMS 14848
#define B_GB2 0
#define B_OB2 4
#define B_HB1 8
#define B_HB2 12
#define B_CB1 14
#define BIAS_OFF (W_ELEMS * 2)
#define ENC_OFF (BIAS_OFF + 960)
#define BLOB_BYTES (ENC_OFF + 768)
#define PREP_ITEMS (W_ELEMS + 240 + 192)

// ws ints: [0..2] counts, [4..6] scatter cursors, [8..10] seg base,
// [11..13] seg tile count, [32..] idx buf

// ============================ fused count (int4, LDS-aggregated) + blob-prep ============================
__global__ void prep_k(const int* __restrict__ levels, int N, int pblocks,
                       const float* __restrict__ g_w1, const float* __restrict__ g_b1,
                       const float* __restrict__ o_w1, const float* __restrict__ o_b1,
                       const float* __restrict__ g_w2, const float* __restrict__ o_w2,
                       const float* __restrict__ h_w1, const float* __restrict__ h_w2,
                       const float* __restrict__ c_w1,
                       const float* __restrict__ g_b2, const float* __restrict__ o_b2,
                       const float* __restrict__ h_b1, const float* __restrict__ h_b2,
                       const float* __restrict__ c_b1,
                       int* __restrict__ ws, char* __restrict__ wb) {
  if ((int)blockIdx.x < pblocks) {
    __shared__ int bc[3];
    if (threadIdx.x < 3) bc[threadIdx.x] = 0;
    __syncthreads();
    int base = ((int)blockIdx.x * 512 + (int)threadIdx.x) * 4;
    int e0 = -1, e1 = -1, e2 = -1, e3 = -1;
    if (base + 3 < N) {
      int4 v = *(const int4*)(levels + base);
      e0 = v.x; e1 = v.y; e2 = v.z; e3 = v.w;
    } else {
      if (base < N)     e0 = levels[base];
      if (base + 1 < N) e1 = levels[base + 1];
      if (base + 2 < N) e2 = levels[base + 2];
      if (base + 3 < N) e3 = levels[base + 3];
    }
    int lane = threadIdx.x & 63;
#pragma unroll
    for (int l = 0; l < 3; ++l) {
      int cnt = (e0 == l) + (e1 == l) + (e2 == l) + (e3 == l);
#pragma unroll
      for (int d = 1; d < 64; d <<= 1) cnt += __shfl_xor(cnt, d);
      if (lane == 0 && cnt) atomicAdd(&bc[l], cnt);
    }
    __syncthreads();
    if (threadIdx.x < 3 && bc[threadIdx.x]) atomicAdd(&ws[threadIdx.x], bc[threadIdx.x]);
    return;
  }
  int i = ((int)blockIdx.x - pblocks) * 512 + threadIdx.x;
  if (i >= 3 * PREP_ITEMS) return;
  int lv = i / PREP_ITEMS;
  int off = i - lv * PREP_ITEMS;
  char* blob = wb + (size_t)lv * BLOB_BYTES;
  if (off < W_ELEMS) {
    int e = off & 3;
    int lane = (off >> 2) & 63;
    int tile = off >> 8;
    const float* W; int NT, N2, tb;
    if (tile < 8)       { W = g_w2;             NT = 4; N2 = 64; tb = tile; }
    else if (tile < 16) { W = o_w2;             NT = 4; N2 = 64; tb = tile - 8; }
    else if (tile < 48) { W = h_w1 + lv * 8192; NT = 4; N2 = 64; tb = tile - 16; }
    else if (tile < 56) { W = h_w2 + lv * 2048; NT = 2; N2 = 32; tb = tile - 48; }
    else                { W = c_w1;             NT = 1; N2 = 16; tb = tile - 56; }
    int nt = tb % NT, kt = tb / NT;
    int k = kt * 16 + ((lane >> 4) << 2) + e;
    int n = nt * 16 + (lane & 15);
    _Float16 h = (_Float16)W[k * N2 + n];
    ((uint16_t*)blob)[off] = __builtin_bit_cast(unsigned short, h);
  } else if (off < W_ELEMS + 240) {
    int b = off - W_ELEMS;
    int fi = b & 15;
    int t = b >> 4;
    const float* B; int base;
    if (t < 4)       { B = g_b2;            base = t * 16; }
    else if (t < 8)  { B = o_b2;            base = (t - 4) * 16; }
    else if (t < 12) { B = h_b1 + lv * 64;  base = (t - 8) * 16; }
    else if (t < 14) { B = h_b2 + lv * 32;  base = (t - 12) * 16; }
    else             { B = c_b1;            base = 0; }
    ((float*)(blob + BIAS_OFF))[b] = B[base + fi];
  } else {
    int e2 = off - (W_ELEMS + 240);   // 0..191
    int gg = e2 / 48, slot = e2 % 48;
    int k = 0, p;
    const float* src; bool isb = false;
    if (slot < 20)      { src = g_w1; k = slot >> 2; p = slot & 3; }
    else if (slot < 40) { src = o_w1; k = (slot - 20) >> 2; p = (slot - 20) & 3; }
    else if (slot < 44) { src = g_b1; p = slot - 40; isb = true; }
    else                { src = o_b1; p = slot - 44; isb = true; }
    int f0 = (p >> 1) * 16 + gg * 4 + (p & 1) * 2;
    float a, b;
    if (isb) { a = src[f0]; b = src[f0 + 1]; }
    else     { a = src[k * 32 + f0]; b = src[k * 32 + f0 + 1]; }
    ((uint32_t*)(blob + ENC_OFF))[e2] = pkh2u(a, b);
  }
}

// ============================ scatter (int4 x4/thread, wave scan) ============================
__global__ void scatter_k(const int* __restrict__ levels, int* __restrict__ ws, int N) {
  int cntl[3], padl[3], Bl[3];
  cntl[0] = ws[0]; cntl[1] = ws[1]; cntl[2] = ws[2];
#pragma unroll
  for (int l = 0; l < 3; ++l) padl[l] = (cntl[l] + 31) & ~31;
  Bl[0] = 0; Bl[1] = padl[0]; Bl[2] = padl[0] + padl[1];
  int* idx = ws + 32;
  if (blockIdx.x == 0) {
    if (threadIdx.x < 3) {
      ws[8 + threadIdx.x] = Bl[threadIdx.x];
      ws[11 + threadIdx.x] = padl[threadIdx.x] >> 5;
    }
#pragma unroll
    for (int l = 0; l < 3; ++l)
      for (int s = cntl[l] + (int)threadIdx.x; s < padl[l]; s += 512) idx[Bl[l] + s] = -1;
  }

  const int lane = threadIdx.x & 63;
  const int wave = threadIdx.x >> 6;
  int base = ((int)blockIdx.x * 512 + (int)threadIdx.x) * 4;
  int e0 = -1, e1 = -1, e2 = -1, e3 = -1;
  if (base + 3 < N) {
    int4 v = *(const int4*)(levels + base);
    e0 = v.x; e1 = v.y; e2 = v.z; e3 = v.w;
  } else {
    if (base < N)     e0 = levels[base];
    if (base + 1 < N) e1 = levels[base + 1];
    if (base + 2 < N) e2 = levels[base + 2];
    if (base + 3 < N) e3 = levels[base + 3];
  }

  __shared__ int wsum[3][8];
  __shared__ int bb[3];
  int texcl0, texcl1, texcl2;
#pragma unroll
  for (int l = 0; l < 3; ++l) {
    int cnt = (e0 == l) + (e1 == l) + (e2 == l) + (e3 == l);
    int v = cnt;
#pragma unroll
    for (int d = 1; d < 64; d <<= 1) {
      int t = __shfl_up(v, d);
      v += (lane >= d) ? t : 0;
    }
    int ex = v - cnt;
    if (l == 0) texcl0 = ex; else if (l == 1) texcl1 = ex; else texcl2 = ex;
    if (lane == 63) wsum[l][wave] = v;
  }
  __syncthreads();
  if (threadIdx.x < 3) {
    int l = threadIdx.x, s = 0;
#pragma unroll
    for (int w = 0; w < 8; ++w) { int t = wsum[l][w]; wsum[l][w] = s; s += t; }
    bb[l] = atomicAdd(&ws[4 + l], s);
  }
  __syncthreads();

  int p0 = Bl[0] + bb[0] + wsum[0][wave] + texcl0;
  int p1 = Bl[1] + bb[1] + wsum[1][wave] + texcl1;
  int p2 = Bl[2] + bb[2] + wsum[2][wave] + texcl2;
#define EMIT(E, K) do {                                  \
    if ((E) == 0)      idx[p0++] = base + (K);           \
    else if ((E) == 1) idx[p1++] = base + (K);           \
    else if ((E) == 2) idx[p2++] = base + (K);           \
  } while (0)
  EMIT(e0, 0);
  EMIT(e1, 1);
  EMIT(e2, 2);
  EMIT(e3, 3);
#undef EMIT
}

// ============================ routed main kernel (R15-proven optimum) ============================
#define NBL 1376                 // blocks per level; grid = 4128; 11008 wave-slots/level
#define JS (8 * NBL)             // j-stride per wave
#define R_SMEM BLOB_BYTES        // 31424 B

__device__ __forceinline__ f32x4 ldbias(const float* bp, int tile, int g) {
  return *(const f32x4*)(bp + tile * 16 + g * 4);
}

// load one row's 10 feats (rid<0 -> row 0, output suppressed later)
#define LOADT(FBUF, RID) do {                                                   \
    const float2* _p = (const float2*)(feats + (size_t)((RID) < 0 ? 0 : (RID)) * 10); \
    _Pragma("unroll")                                                           \
    for (int _i = 0; _i < 5; ++_i) FBUF[_i] = _p[_i];                           \
  } while (0)

// full per-tile network; FBUF = float2[5] (static idx), RIDX = row index or -1
#define TILE_BODY(FBUF, RIDX) do {                                              \
    _Float16 fv[10];                                                            \
    _Pragma("unroll")                                                           \
    for (int i2 = 0; i2 < 5; ++i2) {                                            \
      fv[2 * i2]     = (_Float16)FBUF[i2].x;                                    \
      fv[2 * i2 + 1] = (_Float16)FBUF[i2].y;                                    \
    }                                                                           \
    h2t agp[4], aop[4];                                                         \
    _Pragma("unroll")                                                           \
    for (int p = 0; p < 4; ++p) {                                               \
      h2t a = b1g[p];                                                           \
      _Pragma("unroll")                                                         \
      for (int k = 0; k < 5; ++k) a = w1g[k][p] * fv[k] + a;                    \
      agp[p] = gelu_h2(a);                                                      \
      h2t ao = b1o[p];                                                          \
      _Pragma("unroll")                                                         \
      for (int k = 0; k < 5; ++k) ao = w1o[k][p] * fv[5 + k] + ao;              \
      aop[p] = gelu_h2(ao);                                                     \
    }                                                                           \
    h4t agf[2], aof[2];                                                         \
    _Pragma("unroll")                                                           \
    for (int t = 0; t < 2; ++t) {                                               \
      agf[t] = __builtin_shufflevector(agp[2 * t], agp[2 * t + 1], 0, 1, 2, 3); \
      aof[t] = __builtin_shufflevector(aop[2 * t], aop[2 * t + 1], 0, 1, 2, 3); \
    }                                                                           \
    h4t xf[8];                                                                  \
    _Pragma("unroll")                                                           \
    for (int nt = 0; nt < 4; ++nt) {                                            \
      f32x4 acc = ldbias(bp, B_GB2 + nt, g);                                    \
      acc = MFMA16(ldA(sm, W_GW2, 0 * 4 + nt, lane), agf[0], acc);              \
      acc = MFMA16(ldA(sm, W_GW2, 1 * 4 + nt, lane), agf[1], acc);              \
      xf[nt] = gelupack(acc);                                                   \
    }                                                                           \
    _Pragma("unroll")                                                           \
    for (int nt = 0; nt < 4; ++nt) {                                            \
      f32x4 acc = ldbias(bp, B_OB2 + nt, g);                                    \
      acc = MFMA16(ldA(sm, W_OW2, 0 * 4 + nt, lane), aof[0], acc);              \
      acc = MFMA16(ldA(sm, W_OW2, 1 * 4 + nt, lane), aof[1], acc);              \
      xf[4 + nt] = gelupack(acc);                                               \
    }                                                                           \
    h4t hf[4];                                                                  \
    _Pragma("unroll")                                                           \
    for (int nt = 0; nt < 4; ++nt) {                                            \
      f32x4 acc = ldbias(bp, B_HB1 + nt, g);                                    \
      _Pragma("unroll")                                                         \
      for (int kt = 0; kt < 8; ++kt)                                            \
        acc = MFMA16(ldA(sm, W_HW1, kt * 4 + nt, lane), xf[kt], acc);           \
      hf[nt] = gelupack(acc);                                                   \
    }                                                                           \
    h4t cf[2];                                                                  \
    _Pragma("unroll")                                                           \
    for (int nt = 0; nt < 2; ++nt) {                                            \
      f32x4 acc = ldbias(bp, B_HB2 + nt, g);                                    \
      _Pragma("unroll")                                                         \
      for (int kt = 0; kt < 4; ++kt)                                            \
        acc = MFMA16(ldA(sm, W_HW2, kt * 2 + nt, lane), hf[kt], acc);           \
      cf[nt] = gelupack(acc);                                                   \
    }                                                                           \
    {                                                                           \
      f32x4 acc = ldbias(bp, B_CB1, g);                                         \
      acc = MFMA16(ldA(sm, W_CW1, 0, lane), cf[0], acc);                        \
      acc = MFMA16(ldA(sm, W_CW1, 1, lane), cf[1], acc);                        \
      float s = 0.0f;                                                           \
      _Pragma("unroll")                                                         \
      for (int r = 0; r < 4; ++r) s = __builtin_fmaf(gelu_f(acc[r]), w2v[r], s);\
      s += __shfl_xor(s, 16);                                                   \
      s += __shfl_xor(s, 32);                                                   \
      if (g == 0 && (RIDX) >= 0) out[(RIDX)] = sigmoid_f(s + cb2v);             \
    }                                                                           \
  } while (0)

__global__ __launch_bounds__(512, 4) void spe_routed(
    const float* __restrict__ feats, const int* __restrict__ ws,
    const char* __restrict__ wb,
    const float* __restrict__ c_w2, const float* __restrict__ c_b2,
    float* __restrict__ out) {
  extern __shared__ uint16_t sm[];
  const int lv = blockIdx.x % 3;
  const int bi = blockIdx.x / 3;

  // stage pre-built blob (straight vectorized copy)
  {
    const uint4* src = (const uint4*)(wb + (size_t)lv * BLOB_BYTES);
    uint4* dst = (uint4*)sm;
    for (int i = threadIdx.x; i < BLOB_BYTES / 16; i += 512) dst[i] = src[i];
  }
  __syncthreads();
  const float* bp = (const float*)((const char*)sm + BIAS_OFF);

  const int lane = threadIdx.x & 63;
  const int wave = threadIdx.x >> 6;
  const int c = lane & 15;
  const int g = lane >> 4;
  const int* idxb = ws + 32;
  const int segrow = ws[8 + lv];
  const int ntl = ws[11 + lv];

  // ---- encL1 weights/biases from LDS packed table (broadcast reads) ----
  uint32_t et[48];
  {
    const uint32_t* ep = (const uint32_t*)((const char*)sm + ENC_OFF) + g * 48;
#pragma unroll
    for (int i = 0; i < 48; ++i) et[i] = ep[i];
  }
  h2t w1g[5][4], w1o[5][4], b1g[4], b1o[4];
#pragma unroll
  for (int k = 0; k < 5; ++k)
#pragma unroll
    for (int p = 0; p < 4; ++p) {
      w1g[k][p] = __builtin_bit_cast(h2t, et[k * 4 + p]);
      w1o[k][p] = __builtin_bit_cast(h2t, et[20 + k * 4 + p]);
    }
#pragma unroll
  for (int p = 0; p < 4; ++p) {
    b1g[p] = __builtin_bit_cast(h2t, et[40 + p]);
    b1o[p] = __builtin_bit_cast(h2t, et[44 + p]);
  }
  float w2v[4];
#pragma unroll
  for (int r = 0; r < 4; ++r) w2v[r] = c_w2[g * 4 + r];
  const float cb2v = c_b2[0];

  // ---- main loop: one 32-row j-slot per wave (1 iter typical at NBL=1376) ----
  for (int j = bi * 8 + wave; j < ntl; j += JS) {
    const int rb = segrow + (j << 5);
    const int r0 = idxb[rb + c];
    const int r1 = idxb[rb + 16 + c];
    float2 f0[5], f1[5];
    LOADT(f0, r0);
    TILE_BODY(f0, r0);
    LOADT(f1, r1);
    TILE_BODY(f1, r1);
  }
}

// ============================ flat fallback (bf16) ============================
#define GW2F 0
#define OW2F 2048
#define HW1F 4096
#define HW2F 28672
#define CW1F 34816
#define WFRAG_ELEMS 35328
#define STAGE_PER_WAVE 4352
#define SMEM_BYTES ((WFRAG_ELEMS + 8 * STAGE_PER_WAVE) * 2)

__global__ __launch_bounds__(512, 2) void spe_flat(
    const float* __restrict__ feats, const int* __restrict__ levels,
    const float* __restrict__ g_w1, const float* __restrict__ g_b1,
    const float* __restrict__ g_w2, const float* __restrict__ g_b2,
    const float* __restrict__ o_w1, const float* __restrict__ o_b1,
    const float* __restrict__ o_w2, const float* __restrict__ o_b2,
    const float* __restrict__ h_w1, const float* __restrict__ h_b1,
    const float* __restrict__ h_w2, const float* __restrict__ h_b2,
    const float* __restrict__ c_w1, const float* __restrict__ c_b1,
    const float* __restrict__ c_w2, const float* __restrict__ c_b2,
    float* __restrict__ out) {
  extern __shared__ uint16_t sm[];
  uint16_t* wf = sm;
  stage_mat(g_w2, 32, 1, 4, 64, wf + GW2F);
  stage_mat(o_w2, 32, 1, 4, 64, wf + OW2F);
#pragma unroll
  for (int h = 0; h < 3; ++h) {
    stage_mat(h_w1 + h * 8192, 128, 4, 4, 64, wf + HW1F + h * 8192);
    stage_mat(h_w2 + h * 2048, 64, 2, 2, 32, wf + HW2F + h * 2048);
  }
  stage_mat(c_w1, 32, 1, 1, 16, wf + CW1F);
  __syncthreads();

  const int lane = threadIdx.x & 63;
  const int wave = threadIdx.x >> 6;
  const int c = lane & 15;
  const int g = lane >> 4;
  const int j0 = g << 3;
  uint16_t* xb = sm + WFRAG_ELEMS + wave * STAGE_PER_WAVE;

  float gb1v[8], ob1v[8];
#pragma unroll
  for (int jj = 0; jj < 8; ++jj) { gb1v[jj] = g_b1[j0 + jj]; ob1v[jj] = o_b1[j0 + jj]; }
  float gb2v[4], ob2v[4];
#pragma unroll
  for (int nt = 0; nt < 4; ++nt) { gb2v[nt] = g_b2[nt * 16 + c]; ob2v[nt] = o_b2[nt * 16 + c]; }
  float hb1v[3][4], hb2v[3][2];
#pragma unroll
  for (int h = 0; h < 3; ++h) {
#pragma unroll
    for (int nt = 0; nt < 4; ++nt) hb1v[h][nt] = h_b1[h * 64 + nt * 16 + c];
#pragma unroll
    for (int n2 = 0; n2 < 2; ++n2) hb2v[h][n2] = h_b2[h * 32 + n2 * 16 + c];
  }
  const float cb1v = c_b1[c];
  const float w2v  = c_w2[c];
  const float cb2v = c_b2[0];

  for (int it = 0; it < 4; ++it) {
    const int rowbase = ((blockIdx.x * 8 + wave) * 4 + it) * 32;
    short8 afx[2][4];
    int lvl[2][4];
#pragma unroll
    for (int tt = 0; tt < 2; ++tt) {
      const int tb = rowbase + tt * 16;
      const float* fr = feats + (size_t)(tb + c) * 10;
      float f[10];
#pragma unroll
      for (int i = 0; i < 10; ++i) f[i] = fr[i];
      float h1[8];
#pragma unroll
      for (int jj = 0; jj < 8; ++jj) {
        float a = gb1v[jj];
#pragma unroll
        for (int k = 0; k < 5; ++k) a = __builtin_fmaf(f[k], g_w1[k * 32 + j0 + jj], a);
        h1[jj] = gelu_f(a);
      }
      short8 ag = pack8(h1);
#pragma unroll
      for (int jj = 0; jj < 8; ++jj) {
        float a = ob1v[jj];
#pragma unroll
        for (int k = 0; k < 5; ++k) a = __builtin_fmaf(f[5 + k], o_w1[k * 32 + j0 + jj], a);
        h1[jj] = gelu_f(a);
      }
      short8 ao = pack8(h1);
#pragma unroll
      for (int nt = 0; nt < 4; ++nt) {
        f32x4 acc = {0.f, 0.f, 0.f, 0.f};
        acc = MFMA_BF16(ag, ldfrag(wf, GW2F + nt * 512, lane), acc);
#pragma unroll
        for (int r = 0; r < 4; ++r)
          xb[(tt * 16 + g * 4 + r) * 136 + nt * 16 + c] = bf1(gelu_f(acc[r] + gb2v[nt]));
      }
#pragma unroll
      for (int nt = 0; nt < 4; ++nt) {
        f32x4 acc = {0.f, 0.f, 0.f, 0.f};
        acc = MFMA_BF16(ao, ldfrag(wf, OW2F + nt * 512, lane), acc);
#pragma unroll
        for (int r = 0; r < 4; ++r)
          xb[(tt * 16 + g * 4 + r) * 136 + 64 + nt * 16 + c] = bf1(gelu_f(acc[r] + ob2v[nt]));
      }
#pragma unroll
      for (int kt = 0; kt < 4; ++kt)
        afx[tt][kt] = *(const short8*)(xb + (tt * 16 + c) * 136 + kt * 32 + g * 8);
#pragma unroll
      for (int r = 0; r < 4; ++r) lvl[tt][r] = levels[tb + g * 4 + r];
    }
    float sel[2][2][4];
#pragma unroll
    for (int h = 0; h < 3; ++h) {
      f32x4 a1[2][4];
#pragma unroll
      for (int nt = 0; nt < 4; ++nt) {
        a1[0][nt] = (f32x4){0.f, 0.f, 0.f, 0.f};
        a1[1][nt] = (f32x4){0.f, 0.f, 0.f, 0.f};
#pragma unroll
        for (int kt = 0; kt < 4; ++kt) {
          short8 bfr = ldfrag(wf, HW1F + h * 8192 + (kt * 4 + nt) * 512, lane);
          a1[0][nt] = MFMA_BF16(afx[0][kt], bfr, a1[0][nt]);
          a1[1][nt] = MFMA_BF16(afx[1][kt], bfr, a1[1][nt]);
        }
      }
#pragma unroll
      for (int tt = 0; tt < 2; ++tt)
#pragma unroll
        for (int nt = 0; nt < 4; ++nt)
#pragma unroll
          for (int r = 0; r < 4; ++r)
            xb[(tt * 16 + g * 4 + r) * 136 + nt * 16 + c] = bf1(gelu_f(a1[tt][nt][r] + hb1v[h][nt]));
      short8 afh[2][2];
#pragma unroll
      for (int tt = 0; tt < 2; ++tt)
#pragma unroll
        for (int kt = 0; kt < 2; ++kt)
          afh[tt][kt] = *(const short8*)(xb + (tt * 16 + c) * 136 + kt * 32 + g * 8);
      f32x4 a2[2][2];
#pragma unroll
      for (int n2 = 0; n2 < 2; ++n2) {
        a2[0][n2] = (f32x4){0.f, 0.f, 0.f, 0.f};
        a2[1][n2] = (f32x4){0.f, 0.f, 0.f, 0.f};
#pragma unroll
        for (int kt = 0; kt < 2; ++kt) {
          short8 bfr = ldfrag(wf, HW2F + h * 2048 + (kt * 2 + n2) * 512, lane);
          a2[0][n2] = MFMA_BF16(afh[0][kt], bfr, a2[0][n2]);
          a2[1][n2] = MFMA_BF16(afh[1][kt], bfr, a2[1][n2]);
        }
      }
#pragma unroll
      for (int tt = 0; tt < 2; ++tt)
#pragma unroll
        for (int n2 = 0; n2 < 2; ++n2)
#pragma unroll
          for (int r = 0; r < 4; ++r) {
            float v = gelu_f(a2[tt][n2][r] + hb2v[h][n2]);
            if (h == 0) sel[tt][n2][r] = v;
            else        sel[tt][n2][r] = (lvl[tt][r] == h) ? v : sel[tt][n2][r];
          }
    }
#pragma unroll
    for (int tt = 0; tt < 2; ++tt)
#pragma unroll
      for (int n2 = 0; n2 < 2; ++n2)
#pragma unroll
        for (int r = 0; r < 4; ++r)
          xb[(tt * 16 + g * 4 + r) * 136 + n2 * 16 + c] = bf1(sel[tt][n2][r]);
    short8 cwf = ldfrag(wf, CW1F, lane);
#pragma unroll
    for (int tt = 0; tt < 2; ++tt) {
      short8 afc = *(const short8*)(xb + (tt * 16 + c) * 136 + g * 8);
      f32x4 acc = {0.f, 0.f, 0.f, 0.f};
      acc = MFMA_BF16(afc, cwf, acc);
      float p[4];
#pragma unroll
      for (int r = 0; r < 4; ++r) p[r] = gelu_f(acc[r] + cb1v) * w2v;
#pragma unroll
      for (int m = 1; m < 16; m <<= 1)
#pragma unroll
        for (int r = 0; r < 4; ++r) p[r] += __shfl_xor(p[r], m);
      if (c == 0) {
        float4 o4;
        o4.x = sigmoid_f(p[0] + cb2v);
        o4.y = sigmoid_f(p[1] + cb2v);
        o4.z = sigmoid_f(p[2] + cb2v);
        o4.w = sigmoid_f(p[3] + cb2v);
        *(float4*)(out + rowbase + tt * 16 + g * 4) = o4;
      }
    }
  }
}

// ============================ launch ============================

extern "C" void kernel_launch(void* const* d_in, const int* in_sizes, int n_in,
                              void* d_out, int out_size, void* d_ws, size_t ws_size,
                              hipStream_t stream) {
  (void)n_in; (void)out_size;
  const float* feats  = (const float*)d_in[0];
  const int*   levels = (const int*)d_in[1];
  const float* g_w1 = (const float*)d_in[2];
  const float* g_b1 = (const float*)d_in[3];
  const float* g_w2 = (const float*)d_in[4];
  const float* g_b2 = (const float*)d_in[5];
  const float* o_w1 = (const float*)d_in[6];
  const float* o_b1 = (const float*)d_in[7];
  const float* o_w2 = (const float*)d_in[8];
  const float* o_b2 = (const float*)d_in[9];
  const float* h_w1 = (const float*)d_in[10];
  const float* h_b1 = (const float*)d_in[11];
  const float* h_w2 = (const float*)d_in[12];
  const float* h_b2 = (const float*)d_in[13];
  const float* c_w1 = (const float*)d_in[14];
  const float* c_b1 = (const float*)d_in[15];
  const float* c_w2 = (const float*)d_in[16];
  const float* c_b2 = (const float*)d_in[17];
  float* out = (float*)d_out;
  const int N = in_sizes[1];

  size_t wboff = (((size_t)(32 + N + 96) * sizeof(int)) + 255) & ~(size_t)255;
  size_t need = wboff + (size_t)3 * BLOB_BYTES;
  if (d_ws != nullptr && ws_size >= need) {
    int* ws = (int*)d_ws;
    char* wb = (char*)d_ws + wboff;
    (void)hipMemsetAsync(ws, 0, 128, stream);
    int pblocks = (N + 2047) / 2048;   // 4 elems/thread
    int prepb = (3 * PREP_ITEMS + 511) / 512;
    prep_k<<<pblocks + prepb, 512, 0, stream>>>(
        levels, N, pblocks, g_w1, g_b1, o_w1, o_b1,
        g_w2, o_w2, h_w1, h_w2, c_w1, g_b2, o_b2, h_b1, h_b2, c_b1, ws, wb);
    scatter_k<<<pblocks, 512, 0, stream>>>(levels, ws, N);
    (void)hipFuncSetAttribute(reinterpret_cast<const void*>(spe_routed),
                              hipFuncAttributeMaxDynamicSharedMemorySize, R_SMEM);
    spe_routed<<<3 * NBL, 512, R_SMEM, stream>>>(feats, ws, wb, c_w2, c_b2, out);
  } else {
    (void)hipFuncSetAttribute(reinterpret_cast<const void*>(spe_flat),
                              hipFuncAttributeMaxDynamicSharedMemorySize, SMEM_BYTES);
    spe_flat<<<1024, 512, SMEM_BYTES, stream>>>(
        feats, levels, g_w1, g_b1, g_w2, g_b2, o_w1, o_b1, o_w2, o_b2,
        h_w1, h_b1, h_w2, h_b2, c_w1, c_b1, c_w2, c_b2, out);
  }
}